// Round 1
// baseline (64.543 us; speedup 1.0000x reference)
//
#include <hip/hip_runtime.h>
#include <math.h>

#define NCONCEPT 1024

// out[i] = 0.5 + 0.5 * ( cos(th2)*cos(th1) - sin(th2)*sin(th1)*cos(om1 + ph2) )
// where th1 = instance[i][1], om1 = instance[i][2],
//       ph2 = w[idx[i]][0],  th2 = w[idx[i]][1].
// (instance[i][0] and w[..][2] cancel out of <Z> exactly.)

__global__ __launch_bounds__(256) void vqc_kernel(
    const float* __restrict__ inst,   // [N,3] f32
    const int*   __restrict__ idx,    // [N]   i32
    const float* __restrict__ w,      // [NCONCEPT,3] f32
    float*       __restrict__ out,    // [N]   f32
    int n)
{
    __shared__ float4 tab[NCONCEPT];  // (cos th2, sin th2, cos ph2, sin ph2)

    for (int c = threadIdx.x; c < NCONCEPT; c += blockDim.x) {
        float ph2 = w[c * 3 + 0];
        float th2 = w[c * 3 + 1];
        float sth2, cth2, sph2, cph2;
        __sincosf(th2, &sth2, &cth2);
        __sincosf(ph2, &sph2, &cph2);
        tab[c] = make_float4(cth2, sth2, cph2, sph2);
    }
    __syncthreads();

    const int tid    = blockIdx.x * blockDim.x + threadIdx.x;
    const int stride = gridDim.x * blockDim.x;
    const int nquads = n >> 2;

    const float4* __restrict__ inst4 = (const float4*)inst;
    const int4*   __restrict__ idx4  = (const int4*)idx;
    float4*       __restrict__ out4  = (float4*)out;

    for (int q = tid; q < nquads; q += stride) {
        // 4 elements = 12 floats = 3x float4
        float4 a = inst4[q * 3 + 0];
        float4 b = inst4[q * 3 + 1];
        float4 c = inst4[q * 3 + 2];
        int4   ix = idx4[q];

        // element e: (phi, theta, omega) triplets laid out flat
        float th[4] = { a.y, b.x, b.w, c.z };
        float om[4] = { a.z, b.y, c.x, c.w };
        int   id[4] = { ix.x, ix.y, ix.z, ix.w };

        float res[4];
        #pragma unroll
        for (int e = 0; e < 4; ++e) {
            float4 t = tab[id[e]];       // cth2, sth2, cph2, sph2
            float s1, c1, so, co;
            __sincosf(th[e], &s1, &c1);
            __sincosf(om[e], &so, &co);
            float cop = co * t.z - so * t.w;          // cos(om1 + ph2)
            float z   = t.x * c1 - t.y * s1 * cop;
            res[e] = fmaf(z, 0.5f, 0.5f);
        }
        out4[q] = make_float4(res[0], res[1], res[2], res[3]);
    }

    // scalar tail (n not divisible by 4) — no-op for this problem size
    for (int i = (nquads << 2) + tid; i < n; i += stride) {
        float th1 = inst[i * 3 + 1];
        float om1 = inst[i * 3 + 2];
        float4 t = tab[idx[i]];
        float s1, c1, so, co;
        __sincosf(th1, &s1, &c1);
        __sincosf(om1, &so, &co);
        float cop = co * t.z - so * t.w;
        float z   = t.x * c1 - t.y * s1 * cop;
        out[i] = fmaf(z, 0.5f, 0.5f);
    }
}

extern "C" void kernel_launch(void* const* d_in, const int* in_sizes, int n_in,
                              void* d_out, int out_size, void* d_ws, size_t ws_size,
                              hipStream_t stream) {
    const float* inst = (const float*)d_in[0];   // [B,D,3] f32
    const int*   idx  = (const int*)d_in[1];     // [B,D]   i32
    const float* w    = (const float*)d_in[2];   // [NC,3]  f32
    float*       out  = (float*)d_out;           // [B,D]   f32

    const int n = in_sizes[1];                   // B*D elements
    const int blocks = 2048;                     // grid-stride, ~8 iters/thread
    vqc_kernel<<<blocks, 256, 0, stream>>>(inst, idx, w, out, n);
}